// Round 19
// baseline (176.183 us; speedup 1.0000x reference)
//
#include <hip/hip_runtime.h>
#include <hip/hip_bf16.h>
#include <hip/hip_fp16.h>

#define SEQ 4096
#define DIM 1024
#define NH 16
#define NT (SEQ / 64)
#define NSPLIT 2
#define TPP (NT / NSPLIT)

typedef __attribute__((ext_vector_type(4))) float f32x4;
typedef __attribute__((ext_vector_type(16))) float f32x16;
typedef __attribute__((ext_vector_type(8))) _Float16 half8;
typedef __attribute__((ext_vector_type(4))) _Float16 half4;

typedef const unsigned __attribute__((address_space(1)))* gas_t;
typedef unsigned __attribute__((address_space(3)))* las_t;

#if __has_builtin(__builtin_amdgcn_exp2f)
#define EXP2(x) __builtin_amdgcn_exp2f(x)
#else
#define EXP2(x) exp2f(x)
#endif

// exp(s*0.125) == exp2(s*C), C = 0.125*log2(e)
#define SMC 0.18033688f

// ---------------- fused prep: z<4 -> W transpose+cvt; z==4 -> x fp32->fp16 ----------------
__global__ __launch_bounds__(256) void prep_all(const float* __restrict__ x,
                                                _Float16* __restrict__ xh,
                                                const float* __restrict__ W0,
                                                const float* __restrict__ W1,
                                                const float* __restrict__ W2,
                                                const float* __restrict__ W3,
                                                _Float16* __restrict__ T0,
                                                _Float16* __restrict__ T1,
                                                _Float16* __restrict__ T2,
                                                _Float16* __restrict__ T3) {
  if (blockIdx.z == 4) {
    const int blkid = blockIdx.x * 32 + blockIdx.y;
#pragma unroll
    for (int u = 0; u < 4; u++) {
      int i = blkid * 4096 + u * 1024 + threadIdx.x * 4;
      float4 v = *reinterpret_cast<const float4*>(x + i);
      half4 h;
      h[0] = (_Float16)v.x; h[1] = (_Float16)v.y;
      h[2] = (_Float16)v.z; h[3] = (_Float16)v.w;
      *reinterpret_cast<half4*>(xh + i) = h;
    }
    return;
  }
  const float* W = blockIdx.z == 0 ? W0 : blockIdx.z == 1 ? W1 : blockIdx.z == 2 ? W2 : W3;
  _Float16* Wt = blockIdx.z == 0 ? T0 : blockIdx.z == 1 ? T1 : blockIdx.z == 2 ? T2 : T3;
  __shared__ float t[32][33];
  int bx = blockIdx.x * 32;  // n block
  int by = blockIdx.y * 32;  // k block
  int tx = threadIdx.x & 31, ty = threadIdx.x >> 5;
#pragma unroll
  for (int i = 0; i < 4; i++)
    t[ty + i * 8][tx] = W[(by + ty + i * 8) * DIM + bx + tx];
  __syncthreads();
#pragma unroll
  for (int i = 0; i < 4; i++)
    Wt[(bx + ty + i * 8) * DIM + by + tx] = (_Float16)t[tx][ty + i * 8];
}

// ---------------- GEMM core (m97 structure): C = A @ Bt^T + bias ----------------
// Tile 128(M) x 128(N), BK=32, 4 waves (2x2 quadrants of 64x64), acc 4x4.
// Staging via global_load_lds width=16 into LINEAR unpadded LDS.
// MODE 0: fp16 head-major [n>>6][row][n&63]; MODE 1: fp32 [row][col];
// MODE 2: fp16 [col][rowP], rowP sigma-permuted within each 64-row group:
//         rowP = base64 + i*16 + gswap*4 + r, gswap = ((g&1)<<1)|(g>>1)
template <int MODE>
__device__ __forceinline__ void gemm_body(const _Float16* __restrict__ A,
                                          const _Float16* __restrict__ Bt,
                                          const float* __restrict__ bias,
                                          void* __restrict__ outp,
                                          int M, int N, int Kd, int bmb, int bnb) {
  __shared__ __align__(16) _Float16 As[128][32];
  __shared__ __align__(16) _Float16 Bs[128][32];
  const int tid = threadIdx.x, lane = tid & 63, w = tid >> 6;
  const int bm = bmb * 128, bn = bnb * 128;
  const int l15 = lane & 15, g = lane >> 4, kb = g * 8;
  const int wr = (w >> 1) * 64, wc = (w & 1) * 64;
  const int lr = lane >> 2;
  const int lc = (lane & 3) * 8;
  f32x4 acc[4][4] = {};

  for (int k0 = 0; k0 < Kd; k0 += 32) {
    __syncthreads();
    const _Float16* as0 = A + (size_t)(bm + w * 32 + lr) * Kd + k0 + lc;
    __builtin_amdgcn_global_load_lds((gas_t)(const void*)as0,
                                     (las_t)(void*)&As[w * 32][0], 16, 0, 0);
    __builtin_amdgcn_global_load_lds((gas_t)(const void*)(as0 + (size_t)16 * Kd),
                                     (las_t)(void*)&As[w * 32 + 16][0], 16, 0, 0);
    const _Float16* bs0 = Bt + (size_t)(bn + w * 32 + lr) * Kd + k0 + lc;
    __builtin_amdgcn_global_load_lds((gas_t)(const void*)bs0,
                                     (las_t)(void*)&Bs[w * 32][0], 16, 0, 0);
    __builtin_amdgcn_global_load_lds((gas_t)(const void*)(bs0 + (size_t)16 * Kd),
                                     (las_t)(void*)&Bs[w * 32 + 16][0], 16, 0, 0);
    __syncthreads();

    half8 af[4], bf[4];
#pragma unroll
    for (int i = 0; i < 4; i++)
      af[i] = *reinterpret_cast<const half8*>(&As[wr + i * 16 + l15][kb]);
#pragma unroll
    for (int j = 0; j < 4; j++)
      bf[j] = *reinterpret_cast<const half8*>(&Bs[wc + j * 16 + l15][kb]);
    __builtin_amdgcn_s_setprio(1);
#pragma unroll
    for (int i = 0; i < 4; i++)
#pragma unroll
      for (int j = 0; j < 4; j++)
        acc[i][j] = __builtin_amdgcn_mfma_f32_16x16x32_f16(af[i], bf[j], acc[i][j], 0, 0, 0);
    __builtin_amdgcn_s_setprio(0);
  }

  const int gswap = ((g & 1) << 1) | (g >> 1);
#pragma unroll
  for (int i = 0; i < 4; i++)
#pragma unroll
    for (int j = 0; j < 4; j++) {
      const int col = bn + wc + j * 16 + l15;
      if (MODE == 2) {
        const int rowP = bm + wr + i * 16 + gswap * 4;  // sigma permutation
        half4 hv;
#pragma unroll
        for (int r = 0; r < 4; r++) hv[r] = (_Float16)(acc[i][j][r] + bias[col]);
        *reinterpret_cast<half4*>(&((_Float16*)outp)[(size_t)col * M + rowP]) = hv;
      } else {
        const int row0 = bm + wr + i * 16 + g * 4;
#pragma unroll
        for (int r = 0; r < 4; r++) {
          float vv = acc[i][j][r] + bias[col];
          if (MODE == 0) {
            _Float16* O = (_Float16*)outp;
            O[(((col >> 6) * SEQ) + row0 + r) * 64 + (col & 63)] = (_Float16)vv;
          } else {
            float* O = (float*)outp;
            O[(size_t)(row0 + r) * N + col] = vv;
          }
        }
      }
    }
}

// fused QKV projection: z=0 -> Q (mode0), z=1 -> K (mode0), z=2 -> V (mode2, sigma-permuted)
__global__ __launch_bounds__(256) void gemm_qkv(const _Float16* __restrict__ A,
                                                const _Float16* __restrict__ WqT,
                                                const _Float16* __restrict__ WkT,
                                                const _Float16* __restrict__ WvT,
                                                const float* __restrict__ bq,
                                                const float* __restrict__ bk,
                                                const float* __restrict__ bv,
                                                _Float16* __restrict__ Qd,
                                                _Float16* __restrict__ Kd,
                                                _Float16* __restrict__ Vd) {
  if (blockIdx.z == 0)
    gemm_body<0>(A, WqT, bq, (void*)Qd, SEQ, DIM, DIM, blockIdx.x, blockIdx.y);
  else if (blockIdx.z == 1)
    gemm_body<0>(A, WkT, bk, (void*)Kd, SEQ, DIM, DIM, blockIdx.x, blockIdx.y);
  else
    gemm_body<2>(A, WvT, bv, (void*)Vd, SEQ, DIM, DIM, blockIdx.x, blockIdx.y);
}

__global__ __launch_bounds__(256) void gemm_out(const _Float16* __restrict__ A,
                                                const _Float16* __restrict__ Bt,
                                                const float* __restrict__ bias,
                                                float* __restrict__ out) {
  gemm_body<1>(A, Bt, bias, (void*)out, SEQ, DIM, DIM, blockIdx.x, blockIdx.y);
}

// ---------------- flash attention (8-wave QBLK=256, 2-way KV-split) ----------------
// R18 pipeline exactly; blockIdx.z = key-range part (32 tiles each). Grid 512 =
// 2 blocks/CU = 4 waves/SIMD (was 1 block/CU = 2 waves/SIMD). Partials are
// per-part NORMALIZED fp16 O (bounded by |V|max, fp16-safe) + (m,l) float2.
// Q,K: fp16 [h][s][64]; Vt_g: fp16 [h*64+dv][s] sigma-permuted;
// Op: fp16 [part][h][s][64]; Ml: float2 [part][h][s]
__global__ __launch_bounds__(512) void attn_fwd(const _Float16* __restrict__ Q,
                                                const _Float16* __restrict__ Kh,
                                                const _Float16* __restrict__ Vt_g,
                                                _Float16* __restrict__ Op,
                                                float2* __restrict__ Ml) {
  __shared__ __align__(16) _Float16 Ks[3][64][72];  // [buf][key][d]
  __shared__ __align__(16) _Float16 Vs[3][64][72];  // [buf][dv][key'']
  const int hh = blockIdx.y;
  const int part = blockIdx.z;
  const int q0 = blockIdx.x * 256;
  const int tid = threadIdx.x, lane = tid & 63, w = tid >> 6;
  const int l31 = lane & 31, hq = lane >> 5, h8 = hq * 8;

  const int qrow = q0 + w * 32 + l31;
  const _Float16* qp = Q + ((size_t)hh * SEQ + qrow) * 64;
  half8 qf[4];
#pragma unroll
  for (int d = 0; d < 4; d++)
    qf[d] = *reinterpret_cast<const half8*>(qp + d * 16 + h8);

  f32x16 o[2] = {};
  float m = -1e30f, lsum = 0.f, negmC = 1e30f;
  const f32x16 kZero16 = {};

  const int srow = tid >> 3, sc8 = (tid & 7) * 8;  // 512 threads cover 64x64 tile
  const _Float16* kbase = Kh + (size_t)hh * SEQ * 64;
  const _Float16* vbase = Vt_g + (size_t)hh * 64 * SEQ;

  uint4 kr, vr;
  auto LOADKV = [&](int kt2) {
    kr = *reinterpret_cast<const uint4*>(kbase + (size_t)(kt2 * 64 + srow) * 64 + sc8);
    vr = *reinterpret_cast<const uint4*>(vbase + (size_t)srow * SEQ + kt2 * 64 + sc8);
  };
  auto STAGE = [&](int buf) {
    *reinterpret_cast<uint4*>(&Ks[buf][srow][sc8]) = kr;
    *reinterpret_cast<uint4*>(&Vs[buf][srow][sc8]) = vr;
  };

  auto QK = [&](int tile, f32x16 (&sf)[2]) {
    const int b = tile % 3;
    __builtin_amdgcn_s_setprio(1);
    {
      half8 kf0 = *reinterpret_cast<const half8*>(&Ks[b][l31][h8]);
      half8 kf1 = *reinterpret_cast<const half8*>(&Ks[b][32 + l31][h8]);
      sf[0] = __builtin_amdgcn_mfma_f32_32x32x16_f16(kf0, qf[0], kZero16, 0, 0, 0);
      sf[1] = __builtin_amdgcn_mfma_f32_32x32x16_f16(kf1, qf[0], kZero16, 0, 0, 0);
    }
#pragma unroll
    for (int d = 1; d < 4; d++) {
      half8 kf0 = *reinterpret_cast<const half8*>(&Ks[b][l31][d * 16 + h8]);
      half8 kf1 = *reinterpret_cast<const half8*>(&Ks[b][32 + l31][d * 16 + h8]);
      sf[0] = __builtin_amdgcn_mfma_f32_32x32x16_f16(kf0, qf[d], sf[0], 0, 0, 0);
      sf[1] = __builtin_amdgcn_mfma_f32_32x32x16_f16(kf1, qf[d], sf[1], 0, 0, 0);
    }
    __builtin_amdgcn_s_setprio(0);
  };

  const int t0 = part * TPP, t1 = t0 + TPP;

  auto ITER = [&](int t, f32x16 (&scur)[2], f32x16 (&snext)[2]) {
    if (t + 1 < t1) QK(t + 1, snext);

    // pm via balanced max3-friendly tree
    float t0v = fmaxf(fmaxf(scur[0][0], scur[0][1]), scur[0][2]);
    float t1v = fmaxf(fmaxf(scur[0][3], scur[0][4]), scur[0][5]);
    float t2v = fmaxf(fmaxf(scur[0][6], scur[0][7]), scur[0][8]);
    float t3v = fmaxf(fmaxf(scur[0][9], scur[0][10]), scur[0][11]);
    float t4v = fmaxf(fmaxf(scur[0][12], scur[0][13]), scur[0][14]);
    float t5v = fmaxf(fmaxf(scur[0][15], scur[1][0]), scur[1][1]);
    float t6v = fmaxf(fmaxf(scur[1][2], scur[1][3]), scur[1][4]);
    float t7v = fmaxf(fmaxf(scur[1][5], scur[1][6]), scur[1][7]);
    float t8v = fmaxf(fmaxf(scur[1][8], scur[1][9]), scur[1][10]);
    float t9v = fmaxf(fmaxf(scur[1][11], scur[1][12]), scur[1][13]);
    float tav = fmaxf(scur[1][14], scur[1][15]);
    float u0 = fmaxf(fmaxf(t0v, t1v), t2v);
    float u1 = fmaxf(fmaxf(t3v, t4v), t5v);
    float u2 = fmaxf(fmaxf(t6v, t7v), t8v);
    float u3 = fmaxf(t9v, tav);
    float pm = fmaxf(fmaxf(fmaxf(u0, u1), u2), u3);

    if (__any(pm > m + 64.f)) {  // defer-max: 64 raw = 8 exp-units
      pm = fmaxf(pm, __shfl_xor(pm, 32, 64));
      float mn = fmaxf(m, pm);
      float al = EXP2((m - mn) * SMC);
      m = mn;
      negmC = -mn * SMC;
      lsum *= al;
      o[0] *= al;
      o[1] *= al;
    }
    f32x16 pf0, pf1;
#pragma unroll
    for (int r = 0; r < 16; r++) {
      float p = EXP2(fmaf(scur[0][r], SMC, negmC));
      pf0[r] = p;
      lsum += p;
    }
#pragma unroll
    for (int r = 0; r < 16; r++) {
      float p = EXP2(fmaf(scur[1][r], SMC, negmC));
      pf1[r] = p;
      lsum += p;
    }
    half8 pb[4];
#pragma unroll
    for (int s = 0; s < 4; s++) {
      const int base = (s & 1) * 8;
      unsigned d0, d1, d2, d3;
      if (s < 2) {
        d0 = __builtin_bit_cast(unsigned, __builtin_amdgcn_cvt_pkrtz(pf0[base + 0], pf0[base + 1]));
        d1 = __builtin_bit_cast(unsigned, __builtin_amdgcn_cvt_pkrtz(pf0[base + 2], pf0[base + 3]));
        d2 = __builtin_bit_cast(unsigned, __builtin_amdgcn_cvt_pkrtz(pf0[base + 4], pf0[base + 5]));
        d3 = __builtin_bit_cast(unsigned, __builtin_amdgcn_cvt_pkrtz(pf0[base + 6], pf0[base + 7]));
      } else {
        d0 = __builtin_bit_cast(unsigned, __builtin_amdgcn_cvt_pkrtz(pf1[base + 0], pf1[base + 1]));
        d1 = __builtin_bit_cast(unsigned, __builtin_amdgcn_cvt_pkrtz(pf1[base + 2], pf1[base + 3]));
        d2 = __builtin_bit_cast(unsigned, __builtin_amdgcn_cvt_pkrtz(pf1[base + 4], pf1[base + 5]));
        d3 = __builtin_bit_cast(unsigned, __builtin_amdgcn_cvt_pkrtz(pf1[base + 6], pf1[base + 7]));
      }
      uint4 uu = {d0, d1, d2, d3};
      pb[s] = __builtin_bit_cast(half8, uu);
    }

    const int bv = t % 3;
    __builtin_amdgcn_s_setprio(1);
#pragma unroll
    for (int s = 0; s < 4; s++) {
      half8 va0 = *reinterpret_cast<const half8*>(&Vs[bv][l31][s * 16 + h8]);
      half8 va1 = *reinterpret_cast<const half8*>(&Vs[bv][32 + l31][s * 16 + h8]);
      o[0] = __builtin_amdgcn_mfma_f32_32x32x16_f16(va0, pb[s], o[0], 0, 0, 0);
      o[1] = __builtin_amdgcn_mfma_f32_32x32x16_f16(va1, pb[s], o[1], 0, 0, 0);
    }
    __builtin_amdgcn_s_setprio(0);

    if (t + 2 < t1) STAGE((t + 2) % 3);
    if (t + 3 < t1) LOADKV(t + 3);
    __syncthreads();
  };

  // prologue: stage tiles t0, t0+1; t0+2 in flight
  LOADKV(t0); STAGE(t0 % 3);
  LOADKV(t0 + 1); STAGE((t0 + 1) % 3);
  LOADKV(t0 + 2);
  __syncthreads();

  f32x16 sfA[2], sfB[2];
  QK(t0, sfA);
  for (int t = t0; t < t1; t += 2) {
    ITER(t, sfA, sfB);
    ITER(t + 1, sfB, sfA);
  }

  // per-part normalized fp16 partial + (m, l)
  float ls = lsum + __shfl_xor(lsum, 32, 64);
  float rinv = 1.f / ls;
  const size_t prow = ((size_t)part * NH + hh) * SEQ + qrow;
#pragma unroll
  for (int tile = 0; tile < 2; tile++)
#pragma unroll
    for (int rg = 0; rg < 4; rg++) {
      half4 hv;
#pragma unroll
      for (int j = 0; j < 4; j++) hv[j] = (_Float16)(o[tile][rg * 4 + j] * rinv);
      const int dv = tile * 32 + rg * 8 + 4 * hq;
      *reinterpret_cast<half4*>(&Op[prow * 64 + dv]) = hv;
    }
  if (hq == 0) Ml[prow] = make_float2(m, ls);
}

// ---------------- merge 2 normalized partials -> fp16 Od [s][DIM] ----------------
__global__ __launch_bounds__(256) void attn_merge(const _Float16* __restrict__ Op,
                                                  const float2* __restrict__ Ml,
                                                  _Float16* __restrict__ Og) {
  const int gid = blockIdx.x * 256 + threadIdx.x;
  const int dv4 = (gid & 15) * 4;
  const int row = gid >> 4;       // h*SEQ + s
  const int h = row >> 12, s = row & (SEQ - 1);
  float2 a = Ml[row];
  float2 b = Ml[(size_t)NH * SEQ + row];
  float mm = fmaxf(a.x, b.x);
  float w1 = a.y * EXP2((a.x - mm) * SMC);
  float w2 = b.y * EXP2((b.x - mm) * SMC);
  float rinv = 1.f / (w1 + w2);
  w1 *= rinv; w2 *= rinv;
  half4 o1 = *reinterpret_cast<const half4*>(&Op[(size_t)row * 64 + dv4]);
  half4 o2 = *reinterpret_cast<const half4*>(&Op[((size_t)NH * SEQ + row) * 64 + dv4]);
  half4 hv;
#pragma unroll
  for (int j = 0; j < 4; j++)
    hv[j] = (_Float16)(w1 * (float)o1[j] + w2 * (float)o2[j]);
  *reinterpret_cast<half4*>(&Og[(size_t)s * DIM + h * 64 + dv4]) = hv;
}

// ---------------- launch ----------------

extern "C" void kernel_launch(void* const* d_in, const int* in_sizes, int n_in,
                              void* d_out, int out_size, void* d_ws, size_t ws_size,
                              hipStream_t stream) {
  const float* x  = (const float*)d_in[0];
  const float* Wq = (const float*)d_in[1];
  const float* bq = (const float*)d_in[2];
  const float* Wk = (const float*)d_in[3];
  const float* bk = (const float*)d_in[4];
  const float* Wv = (const float*)d_in[5];
  const float* bv = (const float*)d_in[6];
  const float* Wo = (const float*)d_in[7];
  const float* bo = (const float*)d_in[8];

  char* ws = (char*)d_ws;
  _Float16* xh  = (_Float16*)ws;                         // [SEQ][DIM]
  _Float16* WqT = (_Float16*)(ws + (size_t)SEQ * DIM * 2);
  _Float16* WkT = WqT + DIM * DIM;
  _Float16* WvT = WkT + DIM * DIM;
  _Float16* WoT = WvT + DIM * DIM;
  _Float16* Qd  = WoT + DIM * DIM;                       // [16][SEQ][64]
  _Float16* Kd  = Qd + (size_t)SEQ * DIM;                // [16][SEQ][64]
  _Float16* Vd  = Kd + (size_t)SEQ * DIM;                // [DIM][SEQ] (V^T, sigma-permuted)
  _Float16* Od  = Vd + (size_t)SEQ * DIM;                // [SEQ][DIM]
  _Float16* Opart = Od + (size_t)SEQ * DIM;              // [2][NH][SEQ][64] fp16
  float2*   Mlp   = (float2*)(Opart + (size_t)NSPLIT * NH * SEQ * 64);  // [2][NH][SEQ]

  prep_all<<<dim3(32, 32, 5), 256, 0, stream>>>(x, xh, Wq, Wk, Wv, Wo,
                                                WqT, WkT, WvT, WoT);

  gemm_qkv<<<dim3(SEQ / 128, DIM / 128, 3), 256, 0, stream>>>(
      xh, WqT, WkT, WvT, bq, bk, bv, Qd, Kd, Vd);

  attn_fwd<<<dim3(SEQ / 256, NH, NSPLIT), 512, 0, stream>>>(Qd, Kd, Vd, Opart, Mlp);
  attn_merge<<<(NH * SEQ * 16) / 256, 256, 0, stream>>>(Opart, Mlp, Od);

  gemm_out<<<dim3(SEQ / 128, DIM / 128), 256, 0, stream>>>(Od, WoT, bo, (float*)d_out);
}

// Round 20
// 163.702 us; speedup vs baseline: 1.0762x; 1.0762x over previous
//
#include <hip/hip_runtime.h>
#include <hip/hip_bf16.h>
#include <hip/hip_fp16.h>

#define SEQ 4096
#define DIM 1024
#define NH 16
#define NT (SEQ / 64)

typedef __attribute__((ext_vector_type(4))) float f32x4;
typedef __attribute__((ext_vector_type(16))) float f32x16;
typedef __attribute__((ext_vector_type(8))) _Float16 half8;
typedef __attribute__((ext_vector_type(4))) _Float16 half4;

typedef const unsigned __attribute__((address_space(1)))* gas_t;
typedef unsigned __attribute__((address_space(3)))* las_t;

#if __has_builtin(__builtin_amdgcn_exp2f)
#define EXP2(x) __builtin_amdgcn_exp2f(x)
#else
#define EXP2(x) exp2f(x)
#endif

// exp(s*0.125) == exp2(s*C), C = 0.125*log2(e)
#define SMC 0.18033688f

// ---------------- fused prep: z<4 -> W transpose+cvt; z==4 -> x fp32->fp16 ----------------
__global__ __launch_bounds__(256) void prep_all(const float* __restrict__ x,
                                                _Float16* __restrict__ xh,
                                                const float* __restrict__ W0,
                                                const float* __restrict__ W1,
                                                const float* __restrict__ W2,
                                                const float* __restrict__ W3,
                                                _Float16* __restrict__ T0,
                                                _Float16* __restrict__ T1,
                                                _Float16* __restrict__ T2,
                                                _Float16* __restrict__ T3) {
  if (blockIdx.z == 4) {
    const int blkid = blockIdx.x * 32 + blockIdx.y;
#pragma unroll
    for (int u = 0; u < 4; u++) {
      int i = blkid * 4096 + u * 1024 + threadIdx.x * 4;
      float4 v = *reinterpret_cast<const float4*>(x + i);
      half4 h;
      h[0] = (_Float16)v.x; h[1] = (_Float16)v.y;
      h[2] = (_Float16)v.z; h[3] = (_Float16)v.w;
      *reinterpret_cast<half4*>(xh + i) = h;
    }
    return;
  }
  const float* W = blockIdx.z == 0 ? W0 : blockIdx.z == 1 ? W1 : blockIdx.z == 2 ? W2 : W3;
  _Float16* Wt = blockIdx.z == 0 ? T0 : blockIdx.z == 1 ? T1 : blockIdx.z == 2 ? T2 : T3;
  __shared__ float t[32][33];
  int bx = blockIdx.x * 32;  // n block
  int by = blockIdx.y * 32;  // k block
  int tx = threadIdx.x & 31, ty = threadIdx.x >> 5;
#pragma unroll
  for (int i = 0; i < 4; i++)
    t[ty + i * 8][tx] = W[(by + ty + i * 8) * DIM + bx + tx];
  __syncthreads();
#pragma unroll
  for (int i = 0; i < 4; i++)
    Wt[(bx + ty + i * 8) * DIM + by + tx] = (_Float16)t[tx][ty + i * 8];
}

// ---------------- GEMM core (m97 structure): C = A @ Bt^T + bias ----------------
// Tile 128(M) x 128(N), BK=32, 4 waves (2x2 quadrants of 64x64), acc 4x4.
// Staging via global_load_lds width=16 into LINEAR unpadded LDS.
// MODE 0: fp16 head-major [n>>6][row][n&63]; MODE 1: fp32 [row][col];
// MODE 2: fp16 [col][rowP], rowP sigma-permuted within each 64-row group:
//         rowP = base64 + i*16 + gswap*4 + r, gswap = ((g&1)<<1)|(g>>1)
template <int MODE>
__device__ __forceinline__ void gemm_body(const _Float16* __restrict__ A,
                                          const _Float16* __restrict__ Bt,
                                          const float* __restrict__ bias,
                                          void* __restrict__ outp,
                                          int M, int N, int Kd, int bmb, int bnb) {
  __shared__ __align__(16) _Float16 As[128][32];
  __shared__ __align__(16) _Float16 Bs[128][32];
  const int tid = threadIdx.x, lane = tid & 63, w = tid >> 6;
  const int bm = bmb * 128, bn = bnb * 128;
  const int l15 = lane & 15, g = lane >> 4, kb = g * 8;
  const int wr = (w >> 1) * 64, wc = (w & 1) * 64;
  const int lr = lane >> 2;        // row within 16-row DMA group
  const int lc = (lane & 3) * 8;   // k-element offset within row
  f32x4 acc[4][4] = {};

  for (int k0 = 0; k0 < Kd; k0 += 32) {
    __syncthreads();  // previous compute's ds_reads done, LDS writable
    const _Float16* as0 = A + (size_t)(bm + w * 32 + lr) * Kd + k0 + lc;
    __builtin_amdgcn_global_load_lds((gas_t)(const void*)as0,
                                     (las_t)(void*)&As[w * 32][0], 16, 0, 0);
    __builtin_amdgcn_global_load_lds((gas_t)(const void*)(as0 + (size_t)16 * Kd),
                                     (las_t)(void*)&As[w * 32 + 16][0], 16, 0, 0);
    const _Float16* bs0 = Bt + (size_t)(bn + w * 32 + lr) * Kd + k0 + lc;
    __builtin_amdgcn_global_load_lds((gas_t)(const void*)bs0,
                                     (las_t)(void*)&Bs[w * 32][0], 16, 0, 0);
    __builtin_amdgcn_global_load_lds((gas_t)(const void*)(bs0 + (size_t)16 * Kd),
                                     (las_t)(void*)&Bs[w * 32 + 16][0], 16, 0, 0);
    __syncthreads();  // vmcnt drained before barrier: tile visible

    half8 af[4], bf[4];
#pragma unroll
    for (int i = 0; i < 4; i++)
      af[i] = *reinterpret_cast<const half8*>(&As[wr + i * 16 + l15][kb]);
#pragma unroll
    for (int j = 0; j < 4; j++)
      bf[j] = *reinterpret_cast<const half8*>(&Bs[wc + j * 16 + l15][kb]);
    __builtin_amdgcn_s_setprio(1);
#pragma unroll
    for (int i = 0; i < 4; i++)
#pragma unroll
      for (int j = 0; j < 4; j++)
        acc[i][j] = __builtin_amdgcn_mfma_f32_16x16x32_f16(af[i], bf[j], acc[i][j], 0, 0, 0);
    __builtin_amdgcn_s_setprio(0);
  }

  const int gswap = ((g & 1) << 1) | (g >> 1);
#pragma unroll
  for (int i = 0; i < 4; i++)
#pragma unroll
    for (int j = 0; j < 4; j++) {
      const int col = bn + wc + j * 16 + l15;
      if (MODE == 2) {
        const int rowP = bm + wr + i * 16 + gswap * 4;  // sigma permutation
        half4 hv;
#pragma unroll
        for (int r = 0; r < 4; r++) hv[r] = (_Float16)(acc[i][j][r] + bias[col]);
        *reinterpret_cast<half4*>(&((_Float16*)outp)[(size_t)col * M + rowP]) = hv;
      } else {
        const int row0 = bm + wr + i * 16 + g * 4;
#pragma unroll
        for (int r = 0; r < 4; r++) {
          float vv = acc[i][j][r] + bias[col];
          if (MODE == 0) {
            _Float16* O = (_Float16*)outp;
            O[(((col >> 6) * SEQ) + row0 + r) * 64 + (col & 63)] = (_Float16)vv;
          } else {
            float* O = (float*)outp;
            O[(size_t)(row0 + r) * N + col] = vv;
          }
        }
      }
    }
}

// fused QKV projection: z=0 -> Q (mode0), z=1 -> K (mode0), z=2 -> V (mode2, sigma-permuted)
__global__ __launch_bounds__(256) void gemm_qkv(const _Float16* __restrict__ A,
                                                const _Float16* __restrict__ WqT,
                                                const _Float16* __restrict__ WkT,
                                                const _Float16* __restrict__ WvT,
                                                const float* __restrict__ bq,
                                                const float* __restrict__ bk,
                                                const float* __restrict__ bv,
                                                _Float16* __restrict__ Qd,
                                                _Float16* __restrict__ Kd,
                                                _Float16* __restrict__ Vd) {
  if (blockIdx.z == 0)
    gemm_body<0>(A, WqT, bq, (void*)Qd, SEQ, DIM, DIM, blockIdx.x, blockIdx.y);
  else if (blockIdx.z == 1)
    gemm_body<0>(A, WkT, bk, (void*)Kd, SEQ, DIM, DIM, blockIdx.x, blockIdx.y);
  else
    gemm_body<2>(A, WvT, bv, (void*)Vd, SEQ, DIM, DIM, blockIdx.x, blockIdx.y);
}

__global__ __launch_bounds__(256) void gemm_out(const _Float16* __restrict__ A,
                                                const _Float16* __restrict__ Bt,
                                                const float* __restrict__ bias,
                                                float* __restrict__ out) {
  gemm_body<1>(A, Bt, bias, (void*)out, SEQ, DIM, DIM, blockIdx.x, blockIdx.y);
}

// ---------------- flash attention (8-wave blocks, QBLK=256) ----------------
// R16 pipeline, but 512 threads/block covering 256 q-rows: staging ds_writes and
// global K/V loads per wave HALVE (8 waves share each 64-key tile).
// mfma_f32_32x32x16_f16; lane-local P via sigma permutation (no LDS roundtrip);
// triple-buffered K/V, 1 barrier/iter, QK(t+1) hoisted; defer-max.
// Q,K: fp16 [h][s][64]; Vt_g: fp16 [h*64+dv][s] sigma-permuted; Og: fp16 [s][DIM]
__global__ __launch_bounds__(512) void attn_fwd(const _Float16* __restrict__ Q,
                                                const _Float16* __restrict__ Kh,
                                                const _Float16* __restrict__ Vt_g,
                                                _Float16* __restrict__ Og) {
  __shared__ __align__(16) _Float16 Ks[3][64][72];  // [buf][key][d]
  __shared__ __align__(16) _Float16 Vs[3][64][72];  // [buf][dv][key'']
  const int hh = blockIdx.y;
  const int q0 = blockIdx.x * 256;
  const int tid = threadIdx.x, lane = tid & 63, w = tid >> 6;
  const int l31 = lane & 31, hq = lane >> 5, h8 = hq * 8;

  const int qrow = q0 + w * 32 + l31;
  const _Float16* qp = Q + ((size_t)hh * SEQ + qrow) * 64;
  half8 qf[4];
#pragma unroll
  for (int d = 0; d < 4; d++)
    qf[d] = *reinterpret_cast<const half8*>(qp + d * 16 + h8);

  f32x16 o[2] = {};
  float m = -1e30f, lsum = 0.f, negmC = 1e30f;
  const f32x16 kZero16 = {};

  const int srow = tid >> 3, sc8 = (tid & 7) * 8;  // 512 threads cover 64 rows x 64 cols
  const _Float16* kbase = Kh + (size_t)hh * SEQ * 64;
  const _Float16* vbase = Vt_g + (size_t)hh * 64 * SEQ;

  uint4 kr, vr;
  auto LOADKV = [&](int kt2) {
    kr = *reinterpret_cast<const uint4*>(kbase + (size_t)(kt2 * 64 + srow) * 64 + sc8);
    vr = *reinterpret_cast<const uint4*>(vbase + (size_t)srow * SEQ + kt2 * 64 + sc8);
  };
  auto STAGE = [&](int buf) {
    *reinterpret_cast<uint4*>(&Ks[buf][srow][sc8]) = kr;
    *reinterpret_cast<uint4*>(&Vs[buf][srow][sc8]) = vr;
  };

  // S^T[key][q]: 2 key-tiles x 4 d-steps, A = K frag (row=key), B = Q frag (col=q)
  auto QK = [&](int tile, f32x16 (&sf)[2]) {
    const int b = tile % 3;
    __builtin_amdgcn_s_setprio(1);
    {
      half8 kf0 = *reinterpret_cast<const half8*>(&Ks[b][l31][h8]);
      half8 kf1 = *reinterpret_cast<const half8*>(&Ks[b][32 + l31][h8]);
      sf[0] = __builtin_amdgcn_mfma_f32_32x32x16_f16(kf0, qf[0], kZero16, 0, 0, 0);
      sf[1] = __builtin_amdgcn_mfma_f32_32x32x16_f16(kf1, qf[0], kZero16, 0, 0, 0);
    }
#pragma unroll
    for (int d = 1; d < 4; d++) {
      half8 kf0 = *reinterpret_cast<const half8*>(&Ks[b][l31][d * 16 + h8]);
      half8 kf1 = *reinterpret_cast<const half8*>(&Ks[b][32 + l31][d * 16 + h8]);
      sf[0] = __builtin_amdgcn_mfma_f32_32x32x16_f16(kf0, qf[d], sf[0], 0, 0, 0);
      sf[1] = __builtin_amdgcn_mfma_f32_32x32x16_f16(kf1, qf[d], sf[1], 0, 0, 0);
    }
    __builtin_amdgcn_s_setprio(0);
  };

  // one stage: QK(t+1) ; SM(t) in-register ; PV(t) ; STAGE(t+2) ; LOADKV(t+3) ; barrier
  auto ITER = [&](int t, f32x16 (&scur)[2], f32x16 (&snext)[2]) {
    if (t + 1 < NT) QK(t + 1, snext);

    // pm via balanced max3-friendly tree
    float t0 = fmaxf(fmaxf(scur[0][0], scur[0][1]), scur[0][2]);
    float t1 = fmaxf(fmaxf(scur[0][3], scur[0][4]), scur[0][5]);
    float t2 = fmaxf(fmaxf(scur[0][6], scur[0][7]), scur[0][8]);
    float t3 = fmaxf(fmaxf(scur[0][9], scur[0][10]), scur[0][11]);
    float t4 = fmaxf(fmaxf(scur[0][12], scur[0][13]), scur[0][14]);
    float t5 = fmaxf(fmaxf(scur[0][15], scur[1][0]), scur[1][1]);
    float t6 = fmaxf(fmaxf(scur[1][2], scur[1][3]), scur[1][4]);
    float t7 = fmaxf(fmaxf(scur[1][5], scur[1][6]), scur[1][7]);
    float t8 = fmaxf(fmaxf(scur[1][8], scur[1][9]), scur[1][10]);
    float t9 = fmaxf(fmaxf(scur[1][11], scur[1][12]), scur[1][13]);
    float ta = fmaxf(scur[1][14], scur[1][15]);
    float u0 = fmaxf(fmaxf(t0, t1), t2);
    float u1 = fmaxf(fmaxf(t3, t4), t5);
    float u2 = fmaxf(fmaxf(t6, t7), t8);
    float u3 = fmaxf(t9, ta);
    float pm = fmaxf(fmaxf(fmaxf(u0, u1), u2), u3);

    if (__any(pm > m + 64.f)) {  // defer-max: 64 raw = 8 exp-units
      pm = fmaxf(pm, __shfl_xor(pm, 32, 64));
      float mn = fmaxf(m, pm);
      float al = EXP2((m - mn) * SMC);
      m = mn;
      negmC = -mn * SMC;
      lsum *= al;
      o[0] *= al;
      o[1] *= al;
    }
    f32x16 pf0, pf1;
#pragma unroll
    for (int r = 0; r < 16; r++) {
      float p = EXP2(fmaf(scur[0][r], SMC, negmC));
      pf0[r] = p;
      lsum += p;
    }
#pragma unroll
    for (int r = 0; r < 16; r++) {
      float p = EXP2(fmaf(scur[1][r], SMC, negmC));
      pf1[r] = p;
      lsum += p;
    }
    // pack P into PV B-frags: step s uses regs (s&1)*8.. of tile s>>1 (lane-local)
    half8 pb[4];
#pragma unroll
    for (int s = 0; s < 4; s++) {
      const int base = (s & 1) * 8;
      unsigned d0, d1, d2, d3;
      if (s < 2) {
        d0 = __builtin_bit_cast(unsigned, __builtin_amdgcn_cvt_pkrtz(pf0[base + 0], pf0[base + 1]));
        d1 = __builtin_bit_cast(unsigned, __builtin_amdgcn_cvt_pkrtz(pf0[base + 2], pf0[base + 3]));
        d2 = __builtin_bit_cast(unsigned, __builtin_amdgcn_cvt_pkrtz(pf0[base + 4], pf0[base + 5]));
        d3 = __builtin_bit_cast(unsigned, __builtin_amdgcn_cvt_pkrtz(pf0[base + 6], pf0[base + 7]));
      } else {
        d0 = __builtin_bit_cast(unsigned, __builtin_amdgcn_cvt_pkrtz(pf1[base + 0], pf1[base + 1]));
        d1 = __builtin_bit_cast(unsigned, __builtin_amdgcn_cvt_pkrtz(pf1[base + 2], pf1[base + 3]));
        d2 = __builtin_bit_cast(unsigned, __builtin_amdgcn_cvt_pkrtz(pf1[base + 4], pf1[base + 5]));
        d3 = __builtin_bit_cast(unsigned, __builtin_amdgcn_cvt_pkrtz(pf1[base + 6], pf1[base + 7]));
      }
      uint4 uu = {d0, d1, d2, d3};
      pb[s] = __builtin_bit_cast(half8, uu);
    }

    // O^T[dv][q] += V'' P'' : A = V frag (row=dv), B = pb (in-register)
    const int bv = t % 3;
    __builtin_amdgcn_s_setprio(1);
#pragma unroll
    for (int s = 0; s < 4; s++) {
      half8 va0 = *reinterpret_cast<const half8*>(&Vs[bv][l31][s * 16 + h8]);
      half8 va1 = *reinterpret_cast<const half8*>(&Vs[bv][32 + l31][s * 16 + h8]);
      o[0] = __builtin_amdgcn_mfma_f32_32x32x16_f16(va0, pb[s], o[0], 0, 0, 0);
      o[1] = __builtin_amdgcn_mfma_f32_32x32x16_f16(va1, pb[s], o[1], 0, 0, 0);
    }
    __builtin_amdgcn_s_setprio(0);

    if (t + 2 < NT) STAGE((t + 2) % 3);  // regs from LOADKV(t+2), issued 1 iter ago
    if (t + 3 < NT) LOADKV(t + 3);
    __syncthreads();  // buffer recycle + staging visibility (2-iter slack)
  };

  // prologue: stage tiles 0,1; tile 2 in flight
  LOADKV(0); STAGE(0);
  LOADKV(1); STAGE(1);
  LOADKV(2);
  __syncthreads();

  f32x16 sfA[2], sfB[2];
  QK(0, sfA);
  for (int t = 0; t < NT; t += 2) {
    ITER(t, sfA, sfB);
    ITER(t + 1, sfB, sfA);
  }

  float ls = lsum + __shfl_xor(lsum, 32, 64);
  float rinv = 1.f / ls;
#pragma unroll
  for (int tile = 0; tile < 2; tile++)
#pragma unroll
    for (int rg = 0; rg < 4; rg++) {
      half4 hv;
#pragma unroll
      for (int j = 0; j < 4; j++) hv[j] = (_Float16)(o[tile][rg * 4 + j] * rinv);
      const int dv = tile * 32 + rg * 8 + 4 * hq;
      *reinterpret_cast<half4*>(&Og[(size_t)qrow * DIM + hh * 64 + dv]) = hv;
    }
}

// ---------------- launch ----------------

extern "C" void kernel_launch(void* const* d_in, const int* in_sizes, int n_in,
                              void* d_out, int out_size, void* d_ws, size_t ws_size,
                              hipStream_t stream) {
  const float* x  = (const float*)d_in[0];
  const float* Wq = (const float*)d_in[1];
  const float* bq = (const float*)d_in[2];
  const float* Wk = (const float*)d_in[3];
  const float* bk = (const float*)d_in[4];
  const float* Wv = (const float*)d_in[5];
  const float* bv = (const float*)d_in[6];
  const float* Wo = (const float*)d_in[7];
  const float* bo = (const float*)d_in[8];

  char* ws = (char*)d_ws;
  _Float16* xh  = (_Float16*)ws;                         // [SEQ][DIM]
  _Float16* WqT = (_Float16*)(ws + (size_t)SEQ * DIM * 2);
  _Float16* WkT = WqT + DIM * DIM;
  _Float16* WvT = WkT + DIM * DIM;
  _Float16* WoT = WvT + DIM * DIM;
  _Float16* Qd  = WoT + DIM * DIM;                       // [16][SEQ][64]
  _Float16* Kd  = Qd + (size_t)SEQ * DIM;                // [16][SEQ][64]
  _Float16* Vd  = Kd + (size_t)SEQ * DIM;                // [DIM][SEQ] (V^T, sigma-permuted)
  _Float16* Od  = Vd + (size_t)SEQ * DIM;                // [SEQ][DIM]

  prep_all<<<dim3(32, 32, 5), 256, 0, stream>>>(x, xh, Wq, Wk, Wv, Wo,
                                                WqT, WkT, WvT, WoT);

  gemm_qkv<<<dim3(SEQ / 128, DIM / 128, 3), 256, 0, stream>>>(
      xh, WqT, WkT, WvT, bq, bk, bv, Qd, Kd, Vd);

  attn_fwd<<<dim3(SEQ / 256, NH), 512, 0, stream>>>(Qd, Kd, Vd, Od);

  gemm_out<<<dim3(SEQ / 128, DIM / 128), 256, 0, stream>>>(Od, WoT, bo, (float*)d_out);
}

// Round 21
// 163.492 us; speedup vs baseline: 1.0776x; 1.0013x over previous
//
#include <hip/hip_runtime.h>
#include <hip/hip_bf16.h>
#include <hip/hip_fp16.h>

#define SEQ 4096
#define DIM 1024
#define NH 16
#define NT (SEQ / 64)

typedef __attribute__((ext_vector_type(4))) float f32x4;
typedef __attribute__((ext_vector_type(16))) float f32x16;
typedef __attribute__((ext_vector_type(8))) _Float16 half8;
typedef __attribute__((ext_vector_type(4))) _Float16 half4;

typedef const unsigned __attribute__((address_space(1)))* gas_t;
typedef unsigned __attribute__((address_space(3)))* las_t;

#if __has_builtin(__builtin_amdgcn_exp2f)
#define EXP2(x) __builtin_amdgcn_exp2f(x)
#else
#define EXP2(x) exp2f(x)
#endif

// exp(s*0.125) == exp2(s*C), C = 0.125*log2(e)
#define SMC 0.18033688f

// ---------------- fused prep: z<4 -> W transpose+cvt; z==4 -> x fp32->fp16 ----------------
__global__ __launch_bounds__(256) void prep_all(const float* __restrict__ x,
                                                _Float16* __restrict__ xh,
                                                const float* __restrict__ W0,
                                                const float* __restrict__ W1,
                                                const float* __restrict__ W2,
                                                const float* __restrict__ W3,
                                                _Float16* __restrict__ T0,
                                                _Float16* __restrict__ T1,
                                                _Float16* __restrict__ T2,
                                                _Float16* __restrict__ T3) {
  if (blockIdx.z == 4) {
    const int blkid = blockIdx.x * 32 + blockIdx.y;
#pragma unroll
    for (int u = 0; u < 4; u++) {
      int i = blkid * 4096 + u * 1024 + threadIdx.x * 4;
      float4 v = *reinterpret_cast<const float4*>(x + i);
      half4 h;
      h[0] = (_Float16)v.x; h[1] = (_Float16)v.y;
      h[2] = (_Float16)v.z; h[3] = (_Float16)v.w;
      *reinterpret_cast<half4*>(xh + i) = h;
    }
    return;
  }
  const float* W = blockIdx.z == 0 ? W0 : blockIdx.z == 1 ? W1 : blockIdx.z == 2 ? W2 : W3;
  _Float16* Wt = blockIdx.z == 0 ? T0 : blockIdx.z == 1 ? T1 : blockIdx.z == 2 ? T2 : T3;
  __shared__ float t[32][33];
  int bx = blockIdx.x * 32;  // n block
  int by = blockIdx.y * 32;  // k block
  int tx = threadIdx.x & 31, ty = threadIdx.x >> 5;
#pragma unroll
  for (int i = 0; i < 4; i++)
    t[ty + i * 8][tx] = W[(by + ty + i * 8) * DIM + bx + tx];
  __syncthreads();
#pragma unroll
  for (int i = 0; i < 4; i++)
    Wt[(bx + ty + i * 8) * DIM + by + tx] = (_Float16)t[tx][ty + i * 8];
}

// ---------------- GEMM core (m97 structure): C = A @ Bt^T + bias ----------------
// Tile 128(M) x 128(N), BK=32, 4 waves (2x2 quadrants of 64x64), acc 4x4.
// Staging via global_load_lds width=16 into LINEAR unpadded LDS.
// MODE 0: fp16 head-major [n>>6][row][n&63]; MODE 1: fp32 [row][col];
// MODE 2: fp16 [col][rowP], rowP sigma-permuted within each 64-row group:
//         rowP = base64 + i*16 + gswap*4 + r, gswap = ((g&1)<<1)|(g>>1)
template <int MODE>
__device__ __forceinline__ void gemm_body(const _Float16* __restrict__ A,
                                          const _Float16* __restrict__ Bt,
                                          const float* __restrict__ bias,
                                          void* __restrict__ outp,
                                          int M, int N, int Kd, int bmb, int bnb) {
  __shared__ __align__(16) _Float16 As[128][32];
  __shared__ __align__(16) _Float16 Bs[128][32];
  const int tid = threadIdx.x, lane = tid & 63, w = tid >> 6;
  const int bm = bmb * 128, bn = bnb * 128;
  const int l15 = lane & 15, g = lane >> 4, kb = g * 8;
  const int wr = (w >> 1) * 64, wc = (w & 1) * 64;
  const int lr = lane >> 2;        // row within 16-row DMA group
  const int lc = (lane & 3) * 8;   // k-element offset within row
  f32x4 acc[4][4] = {};

  for (int k0 = 0; k0 < Kd; k0 += 32) {
    __syncthreads();  // previous compute's ds_reads done, LDS writable
    const _Float16* as0 = A + (size_t)(bm + w * 32 + lr) * Kd + k0 + lc;
    __builtin_amdgcn_global_load_lds((gas_t)(const void*)as0,
                                     (las_t)(void*)&As[w * 32][0], 16, 0, 0);
    __builtin_amdgcn_global_load_lds((gas_t)(const void*)(as0 + (size_t)16 * Kd),
                                     (las_t)(void*)&As[w * 32 + 16][0], 16, 0, 0);
    const _Float16* bs0 = Bt + (size_t)(bn + w * 32 + lr) * Kd + k0 + lc;
    __builtin_amdgcn_global_load_lds((gas_t)(const void*)bs0,
                                     (las_t)(void*)&Bs[w * 32][0], 16, 0, 0);
    __builtin_amdgcn_global_load_lds((gas_t)(const void*)(bs0 + (size_t)16 * Kd),
                                     (las_t)(void*)&Bs[w * 32 + 16][0], 16, 0, 0);
    __syncthreads();  // vmcnt drained before barrier: tile visible

    half8 af[4], bf[4];
#pragma unroll
    for (int i = 0; i < 4; i++)
      af[i] = *reinterpret_cast<const half8*>(&As[wr + i * 16 + l15][kb]);
#pragma unroll
    for (int j = 0; j < 4; j++)
      bf[j] = *reinterpret_cast<const half8*>(&Bs[wc + j * 16 + l15][kb]);
    __builtin_amdgcn_s_setprio(1);
#pragma unroll
    for (int i = 0; i < 4; i++)
#pragma unroll
      for (int j = 0; j < 4; j++)
        acc[i][j] = __builtin_amdgcn_mfma_f32_16x16x32_f16(af[i], bf[j], acc[i][j], 0, 0, 0);
    __builtin_amdgcn_s_setprio(0);
  }

  const int gswap = ((g & 1) << 1) | (g >> 1);
#pragma unroll
  for (int i = 0; i < 4; i++)
#pragma unroll
    for (int j = 0; j < 4; j++) {
      const int col = bn + wc + j * 16 + l15;
      if (MODE == 2) {
        const int rowP = bm + wr + i * 16 + gswap * 4;  // sigma permutation
        half4 hv;
#pragma unroll
        for (int r = 0; r < 4; r++) hv[r] = (_Float16)(acc[i][j][r] + bias[col]);
        *reinterpret_cast<half4*>(&((_Float16*)outp)[(size_t)col * M + rowP]) = hv;
      } else {
        const int row0 = bm + wr + i * 16 + g * 4;
#pragma unroll
        for (int r = 0; r < 4; r++) {
          float vv = acc[i][j][r] + bias[col];
          if (MODE == 0) {
            _Float16* O = (_Float16*)outp;
            O[(((col >> 6) * SEQ) + row0 + r) * 64 + (col & 63)] = (_Float16)vv;
          } else {
            float* O = (float*)outp;
            O[(size_t)(row0 + r) * N + col] = vv;
          }
        }
      }
    }
}

// fused QKV projection: z=0 -> Q (mode0), z=1 -> K (mode0), z=2 -> V (mode2, sigma-permuted)
__global__ __launch_bounds__(256) void gemm_qkv(const _Float16* __restrict__ A,
                                                const _Float16* __restrict__ WqT,
                                                const _Float16* __restrict__ WkT,
                                                const _Float16* __restrict__ WvT,
                                                const float* __restrict__ bq,
                                                const float* __restrict__ bk,
                                                const float* __restrict__ bv,
                                                _Float16* __restrict__ Qd,
                                                _Float16* __restrict__ Kd,
                                                _Float16* __restrict__ Vd) {
  if (blockIdx.z == 0)
    gemm_body<0>(A, WqT, bq, (void*)Qd, SEQ, DIM, DIM, blockIdx.x, blockIdx.y);
  else if (blockIdx.z == 1)
    gemm_body<0>(A, WkT, bk, (void*)Kd, SEQ, DIM, DIM, blockIdx.x, blockIdx.y);
  else
    gemm_body<2>(A, WvT, bv, (void*)Vd, SEQ, DIM, DIM, blockIdx.x, blockIdx.y);
}

__global__ __launch_bounds__(256) void gemm_out(const _Float16* __restrict__ A,
                                                const _Float16* __restrict__ Bt,
                                                const float* __restrict__ bias,
                                                float* __restrict__ out) {
  gemm_body<1>(A, Bt, bias, (void*)out, SEQ, DIM, DIM, blockIdx.x, blockIdx.y);
}

// ---------------- flash attention (8-wave blocks, QBLK=256) ----------------
// R18 pipeline; ONLY change vs R20: lsum accumulated in 4 independent partials
// (dep chain 32 -> ~10) combined after the exp block.
// mfma_f32_32x32x16_f16; lane-local P via sigma permutation (no LDS roundtrip);
// triple-buffered K/V, 1 barrier/iter, QK(t+1) hoisted; defer-max.
// Q,K: fp16 [h][s][64]; Vt_g: fp16 [h*64+dv][s] sigma-permuted; Og: fp16 [s][DIM]
__global__ __launch_bounds__(512) void attn_fwd(const _Float16* __restrict__ Q,
                                                const _Float16* __restrict__ Kh,
                                                const _Float16* __restrict__ Vt_g,
                                                _Float16* __restrict__ Og) {
  __shared__ __align__(16) _Float16 Ks[3][64][72];  // [buf][key][d]
  __shared__ __align__(16) _Float16 Vs[3][64][72];  // [buf][dv][key'']
  const int hh = blockIdx.y;
  const int q0 = blockIdx.x * 256;
  const int tid = threadIdx.x, lane = tid & 63, w = tid >> 6;
  const int l31 = lane & 31, hq = lane >> 5, h8 = hq * 8;

  const int qrow = q0 + w * 32 + l31;
  const _Float16* qp = Q + ((size_t)hh * SEQ + qrow) * 64;
  half8 qf[4];
#pragma unroll
  for (int d = 0; d < 4; d++)
    qf[d] = *reinterpret_cast<const half8*>(qp + d * 16 + h8);

  f32x16 o[2] = {};
  float m = -1e30f, lsum = 0.f, negmC = 1e30f;
  const f32x16 kZero16 = {};

  const int srow = tid >> 3, sc8 = (tid & 7) * 8;  // 512 threads cover 64 rows x 64 cols
  const _Float16* kbase = Kh + (size_t)hh * SEQ * 64;
  const _Float16* vbase = Vt_g + (size_t)hh * 64 * SEQ;

  uint4 kr, vr;
  auto LOADKV = [&](int kt2) {
    kr = *reinterpret_cast<const uint4*>(kbase + (size_t)(kt2 * 64 + srow) * 64 + sc8);
    vr = *reinterpret_cast<const uint4*>(vbase + (size_t)srow * SEQ + kt2 * 64 + sc8);
  };
  auto STAGE = [&](int buf) {
    *reinterpret_cast<uint4*>(&Ks[buf][srow][sc8]) = kr;
    *reinterpret_cast<uint4*>(&Vs[buf][srow][sc8]) = vr;
  };

  // S^T[key][q]: 2 key-tiles x 4 d-steps, A = K frag (row=key), B = Q frag (col=q)
  auto QK = [&](int tile, f32x16 (&sf)[2]) {
    const int b = tile % 3;
    __builtin_amdgcn_s_setprio(1);
    {
      half8 kf0 = *reinterpret_cast<const half8*>(&Ks[b][l31][h8]);
      half8 kf1 = *reinterpret_cast<const half8*>(&Ks[b][32 + l31][h8]);
      sf[0] = __builtin_amdgcn_mfma_f32_32x32x16_f16(kf0, qf[0], kZero16, 0, 0, 0);
      sf[1] = __builtin_amdgcn_mfma_f32_32x32x16_f16(kf1, qf[0], kZero16, 0, 0, 0);
    }
#pragma unroll
    for (int d = 1; d < 4; d++) {
      half8 kf0 = *reinterpret_cast<const half8*>(&Ks[b][l31][d * 16 + h8]);
      half8 kf1 = *reinterpret_cast<const half8*>(&Ks[b][32 + l31][d * 16 + h8]);
      sf[0] = __builtin_amdgcn_mfma_f32_32x32x16_f16(kf0, qf[d], sf[0], 0, 0, 0);
      sf[1] = __builtin_amdgcn_mfma_f32_32x32x16_f16(kf1, qf[d], sf[1], 0, 0, 0);
    }
    __builtin_amdgcn_s_setprio(0);
  };

  // one stage: QK(t+1) ; SM(t) in-register ; PV(t) ; STAGE(t+2) ; LOADKV(t+3) ; barrier
  auto ITER = [&](int t, f32x16 (&scur)[2], f32x16 (&snext)[2]) {
    if (t + 1 < NT) QK(t + 1, snext);

    // pm via balanced max3-friendly tree
    float t0 = fmaxf(fmaxf(scur[0][0], scur[0][1]), scur[0][2]);
    float t1 = fmaxf(fmaxf(scur[0][3], scur[0][4]), scur[0][5]);
    float t2 = fmaxf(fmaxf(scur[0][6], scur[0][7]), scur[0][8]);
    float t3 = fmaxf(fmaxf(scur[0][9], scur[0][10]), scur[0][11]);
    float t4 = fmaxf(fmaxf(scur[0][12], scur[0][13]), scur[0][14]);
    float t5 = fmaxf(fmaxf(scur[0][15], scur[1][0]), scur[1][1]);
    float t6 = fmaxf(fmaxf(scur[1][2], scur[1][3]), scur[1][4]);
    float t7 = fmaxf(fmaxf(scur[1][5], scur[1][6]), scur[1][7]);
    float t8 = fmaxf(fmaxf(scur[1][8], scur[1][9]), scur[1][10]);
    float t9 = fmaxf(fmaxf(scur[1][11], scur[1][12]), scur[1][13]);
    float ta = fmaxf(scur[1][14], scur[1][15]);
    float u0 = fmaxf(fmaxf(t0, t1), t2);
    float u1 = fmaxf(fmaxf(t3, t4), t5);
    float u2 = fmaxf(fmaxf(t6, t7), t8);
    float u3 = fmaxf(t9, ta);
    float pm = fmaxf(fmaxf(fmaxf(u0, u1), u2), u3);

    if (__any(pm > m + 64.f)) {  // defer-max: 64 raw = 8 exp-units
      pm = fmaxf(pm, __shfl_xor(pm, 32, 64));
      float mn = fmaxf(m, pm);
      float al = EXP2((m - mn) * SMC);
      m = mn;
      negmC = -mn * SMC;
      lsum *= al;
      o[0] *= al;
      o[1] *= al;
    }
    // exps + 4 independent lsum partials (dep chain 32 -> ~10)
    f32x16 pf0, pf1;
    float s0 = 0.f, s1 = 0.f, s2 = 0.f, s3 = 0.f;
#pragma unroll
    for (int r = 0; r < 16; r += 4) {
      float p0 = EXP2(fmaf(scur[0][r + 0], SMC, negmC));
      float p1 = EXP2(fmaf(scur[0][r + 1], SMC, negmC));
      float p2 = EXP2(fmaf(scur[0][r + 2], SMC, negmC));
      float p3 = EXP2(fmaf(scur[0][r + 3], SMC, negmC));
      pf0[r + 0] = p0; pf0[r + 1] = p1; pf0[r + 2] = p2; pf0[r + 3] = p3;
      s0 += p0; s1 += p1; s2 += p2; s3 += p3;
    }
#pragma unroll
    for (int r = 0; r < 16; r += 4) {
      float p0 = EXP2(fmaf(scur[1][r + 0], SMC, negmC));
      float p1 = EXP2(fmaf(scur[1][r + 1], SMC, negmC));
      float p2 = EXP2(fmaf(scur[1][r + 2], SMC, negmC));
      float p3 = EXP2(fmaf(scur[1][r + 3], SMC, negmC));
      pf1[r + 0] = p0; pf1[r + 1] = p1; pf1[r + 2] = p2; pf1[r + 3] = p3;
      s0 += p0; s1 += p1; s2 += p2; s3 += p3;
    }
    lsum += (s0 + s1) + (s2 + s3);

    // pack P into PV B-frags: step s uses regs (s&1)*8.. of tile s>>1 (lane-local)
    half8 pb[4];
#pragma unroll
    for (int s = 0; s < 4; s++) {
      const int base = (s & 1) * 8;
      unsigned d0, d1, d2, d3;
      if (s < 2) {
        d0 = __builtin_bit_cast(unsigned, __builtin_amdgcn_cvt_pkrtz(pf0[base + 0], pf0[base + 1]));
        d1 = __builtin_bit_cast(unsigned, __builtin_amdgcn_cvt_pkrtz(pf0[base + 2], pf0[base + 3]));
        d2 = __builtin_bit_cast(unsigned, __builtin_amdgcn_cvt_pkrtz(pf0[base + 4], pf0[base + 5]));
        d3 = __builtin_bit_cast(unsigned, __builtin_amdgcn_cvt_pkrtz(pf0[base + 6], pf0[base + 7]));
      } else {
        d0 = __builtin_bit_cast(unsigned, __builtin_amdgcn_cvt_pkrtz(pf1[base + 0], pf1[base + 1]));
        d1 = __builtin_bit_cast(unsigned, __builtin_amdgcn_cvt_pkrtz(pf1[base + 2], pf1[base + 3]));
        d2 = __builtin_bit_cast(unsigned, __builtin_amdgcn_cvt_pkrtz(pf1[base + 4], pf1[base + 5]));
        d3 = __builtin_bit_cast(unsigned, __builtin_amdgcn_cvt_pkrtz(pf1[base + 6], pf1[base + 7]));
      }
      uint4 uu = {d0, d1, d2, d3};
      pb[s] = __builtin_bit_cast(half8, uu);
    }

    // O^T[dv][q] += V'' P'' : A = V frag (row=dv), B = pb (in-register)
    const int bv = t % 3;
    __builtin_amdgcn_s_setprio(1);
#pragma unroll
    for (int s = 0; s < 4; s++) {
      half8 va0 = *reinterpret_cast<const half8*>(&Vs[bv][l31][s * 16 + h8]);
      half8 va1 = *reinterpret_cast<const half8*>(&Vs[bv][32 + l31][s * 16 + h8]);
      o[0] = __builtin_amdgcn_mfma_f32_32x32x16_f16(va0, pb[s], o[0], 0, 0, 0);
      o[1] = __builtin_amdgcn_mfma_f32_32x32x16_f16(va1, pb[s], o[1], 0, 0, 0);
    }
    __builtin_amdgcn_s_setprio(0);

    if (t + 2 < NT) STAGE((t + 2) % 3);  // regs from LOADKV(t+2), issued 1 iter ago
    if (t + 3 < NT) LOADKV(t + 3);
    __syncthreads();  // buffer recycle + staging visibility (2-iter slack)
  };

  // prologue: stage tiles 0,1; tile 2 in flight
  LOADKV(0); STAGE(0);
  LOADKV(1); STAGE(1);
  LOADKV(2);
  __syncthreads();

  f32x16 sfA[2], sfB[2];
  QK(0, sfA);
  for (int t = 0; t < NT; t += 2) {
    ITER(t, sfA, sfB);
    ITER(t + 1, sfB, sfA);
  }

  float ls = lsum + __shfl_xor(lsum, 32, 64);
  float rinv = 1.f / ls;
#pragma unroll
  for (int tile = 0; tile < 2; tile++)
#pragma unroll
    for (int rg = 0; rg < 4; rg++) {
      half4 hv;
#pragma unroll
      for (int j = 0; j < 4; j++) hv[j] = (_Float16)(o[tile][rg * 4 + j] * rinv);
      const int dv = tile * 32 + rg * 8 + 4 * hq;
      *reinterpret_cast<half4*>(&Og[(size_t)qrow * DIM + hh * 64 + dv]) = hv;
    }
}

// ---------------- launch ----------------

extern "C" void kernel_launch(void* const* d_in, const int* in_sizes, int n_in,
                              void* d_out, int out_size, void* d_ws, size_t ws_size,
                              hipStream_t stream) {
  const float* x  = (const float*)d_in[0];
  const float* Wq = (const float*)d_in[1];
  const float* bq = (const float*)d_in[2];
  const float* Wk = (const float*)d_in[3];
  const float* bk = (const float*)d_in[4];
  const float* Wv = (const float*)d_in[5];
  const float* bv = (const float*)d_in[6];
  const float* Wo = (const float*)d_in[7];
  const float* bo = (const float*)d_in[8];

  char* ws = (char*)d_ws;
  _Float16* xh  = (_Float16*)ws;                         // [SEQ][DIM]
  _Float16* WqT = (_Float16*)(ws + (size_t)SEQ * DIM * 2);
  _Float16* WkT = WqT + DIM * DIM;
  _Float16* WvT = WkT + DIM * DIM;
  _Float16* WoT = WvT + DIM * DIM;
  _Float16* Qd  = WoT + DIM * DIM;                       // [16][SEQ][64]
  _Float16* Kd  = Qd + (size_t)SEQ * DIM;                // [16][SEQ][64]
  _Float16* Vd  = Kd + (size_t)SEQ * DIM;                // [DIM][SEQ] (V^T, sigma-permuted)
  _Float16* Od  = Vd + (size_t)SEQ * DIM;                // [SEQ][DIM]

  prep_all<<<dim3(32, 32, 5), 256, 0, stream>>>(x, xh, Wq, Wk, Wv, Wo,
                                                WqT, WkT, WvT, WoT);

  gemm_qkv<<<dim3(SEQ / 128, DIM / 128, 3), 256, 0, stream>>>(
      xh, WqT, WkT, WvT, bq, bk, bv, Qd, Kd, Vd);

  attn_fwd<<<dim3(SEQ / 256, NH), 512, 0, stream>>>(Qd, Kd, Vd, Od);

  gemm_out<<<dim3(SEQ / 128, DIM / 128), 256, 0, stream>>>(Od, WoT, bo, (float*)d_out);
}

// Round 22
// 162.834 us; speedup vs baseline: 1.0820x; 1.0040x over previous
//
#include <hip/hip_runtime.h>
#include <hip/hip_bf16.h>
#include <hip/hip_fp16.h>

#define SEQ 4096
#define DIM 1024
#define NH 16
#define NT (SEQ / 64)

typedef __attribute__((ext_vector_type(4))) float f32x4;
typedef __attribute__((ext_vector_type(16))) float f32x16;
typedef __attribute__((ext_vector_type(8))) _Float16 half8;
typedef __attribute__((ext_vector_type(4))) _Float16 half4;

typedef const unsigned __attribute__((address_space(1)))* gas_t;
typedef unsigned __attribute__((address_space(3)))* las_t;

#if __has_builtin(__builtin_amdgcn_exp2f)
#define EXP2(x) __builtin_amdgcn_exp2f(x)
#else
#define EXP2(x) exp2f(x)
#endif

// exp(s*0.125) == exp2(s*C), C = 0.125*log2(e)
#define SMC 0.18033688f

// ---------------- fused prep: z<4 -> W transpose+cvt; z==4 -> x fp32->fp16 ----------------
__global__ __launch_bounds__(256) void prep_all(const float* __restrict__ x,
                                                _Float16* __restrict__ xh,
                                                const float* __restrict__ W0,
                                                const float* __restrict__ W1,
                                                const float* __restrict__ W2,
                                                const float* __restrict__ W3,
                                                _Float16* __restrict__ T0,
                                                _Float16* __restrict__ T1,
                                                _Float16* __restrict__ T2,
                                                _Float16* __restrict__ T3) {
  if (blockIdx.z == 4) {
    const int blkid = blockIdx.x * 32 + blockIdx.y;
#pragma unroll
    for (int u = 0; u < 4; u++) {
      int i = blkid * 4096 + u * 1024 + threadIdx.x * 4;
      float4 v = *reinterpret_cast<const float4*>(x + i);
      half4 h;
      h[0] = (_Float16)v.x; h[1] = (_Float16)v.y;
      h[2] = (_Float16)v.z; h[3] = (_Float16)v.w;
      *reinterpret_cast<half4*>(xh + i) = h;
    }
    return;
  }
  const float* W = blockIdx.z == 0 ? W0 : blockIdx.z == 1 ? W1 : blockIdx.z == 2 ? W2 : W3;
  _Float16* Wt = blockIdx.z == 0 ? T0 : blockIdx.z == 1 ? T1 : blockIdx.z == 2 ? T2 : T3;
  __shared__ float t[32][33];
  int bx = blockIdx.x * 32;  // n block
  int by = blockIdx.y * 32;  // k block
  int tx = threadIdx.x & 31, ty = threadIdx.x >> 5;
#pragma unroll
  for (int i = 0; i < 4; i++)
    t[ty + i * 8][tx] = W[(by + ty + i * 8) * DIM + bx + tx];
  __syncthreads();
#pragma unroll
  for (int i = 0; i < 4; i++)
    Wt[(bx + ty + i * 8) * DIM + by + tx] = (_Float16)t[tx][ty + i * 8];
}

// ---------------- GEMM core (m97 structure): C = A @ Bt^T + bias ----------------
// Tile 128(M) x 128(N), BK=32, 4 waves (2x2 quadrants of 64x64), acc 4x4.
// Staging via global_load_lds width=16 into LINEAR unpadded LDS.
// MODE 0: fp16 head-major [n>>6][row][n&63]; MODE 1: fp32 [row][col];
// MODE 2: fp16 [col][rowP], rowP sigma-permuted within each 64-row group:
//         rowP = base64 + i*16 + gswap*4 + r, gswap = ((g&1)<<1)|(g>>1)
template <int MODE>
__device__ __forceinline__ void gemm_body(const _Float16* __restrict__ A,
                                          const _Float16* __restrict__ Bt,
                                          const float* __restrict__ bias,
                                          void* __restrict__ outp,
                                          int M, int N, int Kd, int bmb, int bnb) {
  __shared__ __align__(16) _Float16 As[128][32];
  __shared__ __align__(16) _Float16 Bs[128][32];
  const int tid = threadIdx.x, lane = tid & 63, w = tid >> 6;
  const int bm = bmb * 128, bn = bnb * 128;
  const int l15 = lane & 15, g = lane >> 4, kb = g * 8;
  const int wr = (w >> 1) * 64, wc = (w & 1) * 64;
  const int lr = lane >> 2;        // row within 16-row DMA group
  const int lc = (lane & 3) * 8;   // k-element offset within row
  f32x4 acc[4][4] = {};

  for (int k0 = 0; k0 < Kd; k0 += 32) {
    __syncthreads();  // previous compute's ds_reads done, LDS writable
    const _Float16* as0 = A + (size_t)(bm + w * 32 + lr) * Kd + k0 + lc;
    __builtin_amdgcn_global_load_lds((gas_t)(const void*)as0,
                                     (las_t)(void*)&As[w * 32][0], 16, 0, 0);
    __builtin_amdgcn_global_load_lds((gas_t)(const void*)(as0 + (size_t)16 * Kd),
                                     (las_t)(void*)&As[w * 32 + 16][0], 16, 0, 0);
    const _Float16* bs0 = Bt + (size_t)(bn + w * 32 + lr) * Kd + k0 + lc;
    __builtin_amdgcn_global_load_lds((gas_t)(const void*)bs0,
                                     (las_t)(void*)&Bs[w * 32][0], 16, 0, 0);
    __builtin_amdgcn_global_load_lds((gas_t)(const void*)(bs0 + (size_t)16 * Kd),
                                     (las_t)(void*)&Bs[w * 32 + 16][0], 16, 0, 0);
    __syncthreads();  // vmcnt drained before barrier: tile visible

    half8 af[4], bf[4];
#pragma unroll
    for (int i = 0; i < 4; i++)
      af[i] = *reinterpret_cast<const half8*>(&As[wr + i * 16 + l15][kb]);
#pragma unroll
    for (int j = 0; j < 4; j++)
      bf[j] = *reinterpret_cast<const half8*>(&Bs[wc + j * 16 + l15][kb]);
    __builtin_amdgcn_s_setprio(1);
#pragma unroll
    for (int i = 0; i < 4; i++)
#pragma unroll
      for (int j = 0; j < 4; j++)
        acc[i][j] = __builtin_amdgcn_mfma_f32_16x16x32_f16(af[i], bf[j], acc[i][j], 0, 0, 0);
    __builtin_amdgcn_s_setprio(0);
  }

  const int gswap = ((g & 1) << 1) | (g >> 1);
#pragma unroll
  for (int i = 0; i < 4; i++)
#pragma unroll
    for (int j = 0; j < 4; j++) {
      const int col = bn + wc + j * 16 + l15;
      if (MODE == 2) {
        const int rowP = bm + wr + i * 16 + gswap * 4;  // sigma permutation
        half4 hv;
#pragma unroll
        for (int r = 0; r < 4; r++) hv[r] = (_Float16)(acc[i][j][r] + bias[col]);
        *reinterpret_cast<half4*>(&((_Float16*)outp)[(size_t)col * M + rowP]) = hv;
      } else {
        const int row0 = bm + wr + i * 16 + g * 4;
#pragma unroll
        for (int r = 0; r < 4; r++) {
          float vv = acc[i][j][r] + bias[col];
          if (MODE == 0) {
            _Float16* O = (_Float16*)outp;
            O[(((col >> 6) * SEQ) + row0 + r) * 64 + (col & 63)] = (_Float16)vv;
          } else {
            float* O = (float*)outp;
            O[(size_t)(row0 + r) * N + col] = vv;
          }
        }
      }
    }
}

// fused QKV projection: z=0 -> Q (mode0), z=1 -> K (mode0), z=2 -> V (mode2, sigma-permuted)
__global__ __launch_bounds__(256) void gemm_qkv(const _Float16* __restrict__ A,
                                                const _Float16* __restrict__ WqT,
                                                const _Float16* __restrict__ WkT,
                                                const _Float16* __restrict__ WvT,
                                                const float* __restrict__ bq,
                                                const float* __restrict__ bk,
                                                const float* __restrict__ bv,
                                                _Float16* __restrict__ Qd,
                                                _Float16* __restrict__ Kd,
                                                _Float16* __restrict__ Vd) {
  if (blockIdx.z == 0)
    gemm_body<0>(A, WqT, bq, (void*)Qd, SEQ, DIM, DIM, blockIdx.x, blockIdx.y);
  else if (blockIdx.z == 1)
    gemm_body<0>(A, WkT, bk, (void*)Kd, SEQ, DIM, DIM, blockIdx.x, blockIdx.y);
  else
    gemm_body<2>(A, WvT, bv, (void*)Vd, SEQ, DIM, DIM, blockIdx.x, blockIdx.y);
}

__global__ __launch_bounds__(256) void gemm_out(const _Float16* __restrict__ A,
                                                const _Float16* __restrict__ Bt,
                                                const float* __restrict__ bias,
                                                float* __restrict__ out) {
  gemm_body<1>(A, Bt, bias, (void*)out, SEQ, DIM, DIM, blockIdx.x, blockIdx.y);
}

// ---------------- flash attention (8-wave blocks, QBLK=256) ----------------
// ONLY change vs R21: STAGE(t+2)+LOADKV(t+3) moved to immediately after QK(t+1)
// (before the softmax) — the DS writes/VMEM issue overlap the SM VALU block and
// PV MFMAs instead of forming a serial tail before the barrier. Buffer indices
// are distinct mod 3 (QK reads (t+1)%3, PV reads t%3, STAGE writes (t+2)%3,
// whose last reader finished before the PREVIOUS iteration's barrier).
// mfma_f32_32x32x16_f16; lane-local P via sigma permutation; defer-max.
// Q,K: fp16 [h][s][64]; Vt_g: fp16 [h*64+dv][s] sigma-permuted; Og: fp16 [s][DIM]
__global__ __launch_bounds__(512) void attn_fwd(const _Float16* __restrict__ Q,
                                                const _Float16* __restrict__ Kh,
                                                const _Float16* __restrict__ Vt_g,
                                                _Float16* __restrict__ Og) {
  __shared__ __align__(16) _Float16 Ks[3][64][72];  // [buf][key][d]
  __shared__ __align__(16) _Float16 Vs[3][64][72];  // [buf][dv][key'']
  const int hh = blockIdx.y;
  const int q0 = blockIdx.x * 256;
  const int tid = threadIdx.x, lane = tid & 63, w = tid >> 6;
  const int l31 = lane & 31, hq = lane >> 5, h8 = hq * 8;

  const int qrow = q0 + w * 32 + l31;
  const _Float16* qp = Q + ((size_t)hh * SEQ + qrow) * 64;
  half8 qf[4];
#pragma unroll
  for (int d = 0; d < 4; d++)
    qf[d] = *reinterpret_cast<const half8*>(qp + d * 16 + h8);

  f32x16 o[2] = {};
  float m = -1e30f, lsum = 0.f, negmC = 1e30f;
  const f32x16 kZero16 = {};

  const int srow = tid >> 3, sc8 = (tid & 7) * 8;  // 512 threads cover 64 rows x 64 cols
  const _Float16* kbase = Kh + (size_t)hh * SEQ * 64;
  const _Float16* vbase = Vt_g + (size_t)hh * 64 * SEQ;

  uint4 kr, vr;
  auto LOADKV = [&](int kt2) {
    kr = *reinterpret_cast<const uint4*>(kbase + (size_t)(kt2 * 64 + srow) * 64 + sc8);
    vr = *reinterpret_cast<const uint4*>(vbase + (size_t)srow * SEQ + kt2 * 64 + sc8);
  };
  auto STAGE = [&](int buf) {
    *reinterpret_cast<uint4*>(&Ks[buf][srow][sc8]) = kr;
    *reinterpret_cast<uint4*>(&Vs[buf][srow][sc8]) = vr;
  };

  // S^T[key][q]: 2 key-tiles x 4 d-steps, A = K frag (row=key), B = Q frag (col=q)
  auto QK = [&](int tile, f32x16 (&sf)[2]) {
    const int b = tile % 3;
    __builtin_amdgcn_s_setprio(1);
    {
      half8 kf0 = *reinterpret_cast<const half8*>(&Ks[b][l31][h8]);
      half8 kf1 = *reinterpret_cast<const half8*>(&Ks[b][32 + l31][h8]);
      sf[0] = __builtin_amdgcn_mfma_f32_32x32x16_f16(kf0, qf[0], kZero16, 0, 0, 0);
      sf[1] = __builtin_amdgcn_mfma_f32_32x32x16_f16(kf1, qf[0], kZero16, 0, 0, 0);
    }
#pragma unroll
    for (int d = 1; d < 4; d++) {
      half8 kf0 = *reinterpret_cast<const half8*>(&Ks[b][l31][d * 16 + h8]);
      half8 kf1 = *reinterpret_cast<const half8*>(&Ks[b][32 + l31][d * 16 + h8]);
      sf[0] = __builtin_amdgcn_mfma_f32_32x32x16_f16(kf0, qf[d], sf[0], 0, 0, 0);
      sf[1] = __builtin_amdgcn_mfma_f32_32x32x16_f16(kf1, qf[d], sf[1], 0, 0, 0);
    }
    __builtin_amdgcn_s_setprio(0);
  };

  // one stage: QK(t+1) ; STAGE(t+2) ; LOADKV(t+3) ; SM(t) ; PV(t) ; barrier
  auto ITER = [&](int t, f32x16 (&scur)[2], f32x16 (&snext)[2]) {
    if (t + 1 < NT) QK(t + 1, snext);
    if (t + 2 < NT) STAGE((t + 2) % 3);  // overlaps SM VALU + PV MFMA below
    if (t + 3 < NT) LOADKV(t + 3);

    // pm via balanced max3-friendly tree
    float t0 = fmaxf(fmaxf(scur[0][0], scur[0][1]), scur[0][2]);
    float t1 = fmaxf(fmaxf(scur[0][3], scur[0][4]), scur[0][5]);
    float t2 = fmaxf(fmaxf(scur[0][6], scur[0][7]), scur[0][8]);
    float t3 = fmaxf(fmaxf(scur[0][9], scur[0][10]), scur[0][11]);
    float t4 = fmaxf(fmaxf(scur[0][12], scur[0][13]), scur[0][14]);
    float t5 = fmaxf(fmaxf(scur[0][15], scur[1][0]), scur[1][1]);
    float t6 = fmaxf(fmaxf(scur[1][2], scur[1][3]), scur[1][4]);
    float t7 = fmaxf(fmaxf(scur[1][5], scur[1][6]), scur[1][7]);
    float t8 = fmaxf(fmaxf(scur[1][8], scur[1][9]), scur[1][10]);
    float t9 = fmaxf(fmaxf(scur[1][11], scur[1][12]), scur[1][13]);
    float ta = fmaxf(scur[1][14], scur[1][15]);
    float u0 = fmaxf(fmaxf(t0, t1), t2);
    float u1 = fmaxf(fmaxf(t3, t4), t5);
    float u2 = fmaxf(fmaxf(t6, t7), t8);
    float u3 = fmaxf(t9, ta);
    float pm = fmaxf(fmaxf(fmaxf(u0, u1), u2), u3);

    if (__any(pm > m + 64.f)) {  // defer-max: 64 raw = 8 exp-units
      pm = fmaxf(pm, __shfl_xor(pm, 32, 64));
      float mn = fmaxf(m, pm);
      float al = EXP2((m - mn) * SMC);
      m = mn;
      negmC = -mn * SMC;
      lsum *= al;
      o[0] *= al;
      o[1] *= al;
    }
    // exps + 4 independent lsum partials (dep chain 32 -> ~10)
    f32x16 pf0, pf1;
    float s0 = 0.f, s1 = 0.f, s2 = 0.f, s3 = 0.f;
#pragma unroll
    for (int r = 0; r < 16; r += 4) {
      float p0 = EXP2(fmaf(scur[0][r + 0], SMC, negmC));
      float p1 = EXP2(fmaf(scur[0][r + 1], SMC, negmC));
      float p2 = EXP2(fmaf(scur[0][r + 2], SMC, negmC));
      float p3 = EXP2(fmaf(scur[0][r + 3], SMC, negmC));
      pf0[r + 0] = p0; pf0[r + 1] = p1; pf0[r + 2] = p2; pf0[r + 3] = p3;
      s0 += p0; s1 += p1; s2 += p2; s3 += p3;
    }
#pragma unroll
    for (int r = 0; r < 16; r += 4) {
      float p0 = EXP2(fmaf(scur[1][r + 0], SMC, negmC));
      float p1 = EXP2(fmaf(scur[1][r + 1], SMC, negmC));
      float p2 = EXP2(fmaf(scur[1][r + 2], SMC, negmC));
      float p3 = EXP2(fmaf(scur[1][r + 3], SMC, negmC));
      pf1[r + 0] = p0; pf1[r + 1] = p1; pf1[r + 2] = p2; pf1[r + 3] = p3;
      s0 += p0; s1 += p1; s2 += p2; s3 += p3;
    }
    lsum += (s0 + s1) + (s2 + s3);

    // pack P into PV B-frags: step s uses regs (s&1)*8.. of tile s>>1 (lane-local)
    half8 pb[4];
#pragma unroll
    for (int s = 0; s < 4; s++) {
      const int base = (s & 1) * 8;
      unsigned d0, d1, d2, d3;
      if (s < 2) {
        d0 = __builtin_bit_cast(unsigned, __builtin_amdgcn_cvt_pkrtz(pf0[base + 0], pf0[base + 1]));
        d1 = __builtin_bit_cast(unsigned, __builtin_amdgcn_cvt_pkrtz(pf0[base + 2], pf0[base + 3]));
        d2 = __builtin_bit_cast(unsigned, __builtin_amdgcn_cvt_pkrtz(pf0[base + 4], pf0[base + 5]));
        d3 = __builtin_bit_cast(unsigned, __builtin_amdgcn_cvt_pkrtz(pf0[base + 6], pf0[base + 7]));
      } else {
        d0 = __builtin_bit_cast(unsigned, __builtin_amdgcn_cvt_pkrtz(pf1[base + 0], pf1[base + 1]));
        d1 = __builtin_bit_cast(unsigned, __builtin_amdgcn_cvt_pkrtz(pf1[base + 2], pf1[base + 3]));
        d2 = __builtin_bit_cast(unsigned, __builtin_amdgcn_cvt_pkrtz(pf1[base + 4], pf1[base + 5]));
        d3 = __builtin_bit_cast(unsigned, __builtin_amdgcn_cvt_pkrtz(pf1[base + 6], pf1[base + 7]));
      }
      uint4 uu = {d0, d1, d2, d3};
      pb[s] = __builtin_bit_cast(half8, uu);
    }

    // O^T[dv][q] += V'' P'' : A = V frag (row=dv), B = pb (in-register)
    const int bv = t % 3;
    __builtin_amdgcn_s_setprio(1);
#pragma unroll
    for (int s = 0; s < 4; s++) {
      half8 va0 = *reinterpret_cast<const half8*>(&Vs[bv][l31][s * 16 + h8]);
      half8 va1 = *reinterpret_cast<const half8*>(&Vs[bv][32 + l31][s * 16 + h8]);
      o[0] = __builtin_amdgcn_mfma_f32_32x32x16_f16(va0, pb[s], o[0], 0, 0, 0);
      o[1] = __builtin_amdgcn_mfma_f32_32x32x16_f16(va1, pb[s], o[1], 0, 0, 0);
    }
    __builtin_amdgcn_s_setprio(0);

    __syncthreads();  // buffer recycle + staging visibility (2-iter slack)
  };

  // prologue: stage tiles 0,1; tile 2 in flight
  LOADKV(0); STAGE(0);
  LOADKV(1); STAGE(1);
  LOADKV(2);
  __syncthreads();

  f32x16 sfA[2], sfB[2];
  QK(0, sfA);
  for (int t = 0; t < NT; t += 2) {
    ITER(t, sfA, sfB);
    ITER(t + 1, sfB, sfA);
  }

  float ls = lsum + __shfl_xor(lsum, 32, 64);
  float rinv = 1.f / ls;
#pragma unroll
  for (int tile = 0; tile < 2; tile++)
#pragma unroll
    for (int rg = 0; rg < 4; rg++) {
      half4 hv;
#pragma unroll
      for (int j = 0; j < 4; j++) hv[j] = (_Float16)(o[tile][rg * 4 + j] * rinv);
      const int dv = tile * 32 + rg * 8 + 4 * hq;
      *reinterpret_cast<half4*>(&Og[(size_t)qrow * DIM + hh * 64 + dv]) = hv;
    }
}

// ---------------- launch ----------------

extern "C" void kernel_launch(void* const* d_in, const int* in_sizes, int n_in,
                              void* d_out, int out_size, void* d_ws, size_t ws_size,
                              hipStream_t stream) {
  const float* x  = (const float*)d_in[0];
  const float* Wq = (const float*)d_in[1];
  const float* bq = (const float*)d_in[2];
  const float* Wk = (const float*)d_in[3];
  const float* bk = (const float*)d_in[4];
  const float* Wv = (const float*)d_in[5];
  const float* bv = (const float*)d_in[6];
  const float* Wo = (const float*)d_in[7];
  const float* bo = (const float*)d_in[8];

  char* ws = (char*)d_ws;
  _Float16* xh  = (_Float16*)ws;                         // [SEQ][DIM]
  _Float16* WqT = (_Float16*)(ws + (size_t)SEQ * DIM * 2);
  _Float16* WkT = WqT + DIM * DIM;
  _Float16* WvT = WkT + DIM * DIM;
  _Float16* WoT = WvT + DIM * DIM;
  _Float16* Qd  = WoT + DIM * DIM;                       // [16][SEQ][64]
  _Float16* Kd  = Qd + (size_t)SEQ * DIM;                // [16][SEQ][64]
  _Float16* Vd  = Kd + (size_t)SEQ * DIM;                // [DIM][SEQ] (V^T, sigma-permuted)
  _Float16* Od  = Vd + (size_t)SEQ * DIM;                // [SEQ][DIM]

  prep_all<<<dim3(32, 32, 5), 256, 0, stream>>>(x, xh, Wq, Wk, Wv, Wo,
                                                WqT, WkT, WvT, WoT);

  gemm_qkv<<<dim3(SEQ / 128, DIM / 128, 3), 256, 0, stream>>>(
      xh, WqT, WkT, WvT, bq, bk, bv, Qd, Kd, Vd);

  attn_fwd<<<dim3(SEQ / 256, NH), 512, 0, stream>>>(Qd, Kd, Vd, Od);

  gemm_out<<<dim3(SEQ / 128, DIM / 128), 256, 0, stream>>>(Od, WoT, bo, (float*)d_out);
}